// Round 1
// baseline (8732.317 us; speedup 1.0000x reference)
//
#include <hip/hip_runtime.h>
#include <math.h>

#define BB 256
#define TIN 32
#define TOUT 29
#define VDEC 72
#define EDIM 256
#define HDIM 256
#define GDIM 1024
#define DD 6
#define BH (BB*HDIM)

__device__ __forceinline__ float sigmf(float x){ return 1.0f/(1.0f+expf(-x)); }

// ---------------- init / small kernels ----------------

__global__ void fill_zero_kernel(float* __restrict__ p, int n){
  int i = blockIdx.x*256 + threadIdx.x;
  if (i < n) p[i] = 0.0f;
}

__global__ void init_out_kernel(float* __restrict__ out, int n){
  int i = blockIdx.x*256 + threadIdx.x;
  if (i >= n) return;
  float v = 0.0f;
  // predicted[0, b, 1] = 1.0 ; everything else (incl. all attn weights) = 0
  if (i < BB*VDEC && (i % VDEC) == 1) v = 1.0f;
  out[i] = v;
}

// bias2d[p][m][g] = (sum_l W2[m,l]) * b1[g] + b2[m]   (p: 0=a, 1=h, 2=c)
__global__ void bias2d_kernel(const float* __restrict__ W2a, const float* __restrict__ b1a, const float* __restrict__ b2a,
                              const float* __restrict__ W2h, const float* __restrict__ b1h, const float* __restrict__ b2h,
                              const float* __restrict__ W2c, const float* __restrict__ b1c, const float* __restrict__ b2c,
                              float* __restrict__ outp){
  int g = threadIdx.x;
  const float* W2[3] = {W2a, W2h, W2c};
  const float* b1[3] = {b1a, b1h, b1c};
  const float* b2[3] = {b2a, b2h, b2c};
  for (int p = 0; p < 3; p++)
    for (int m = 0; m < 6; m++){
      float s = 0.f;
      for (int l = 0; l < 6; l++) s += W2[p][m*6+l];
      outp[p*1536 + m*256 + g] = s * b1[p][g] + b2[p][m];
    }
}

__global__ void embed_enc_kernel(const int* __restrict__ input, const float* __restrict__ enc_emb,
                                 float* __restrict__ x_emb){
  int i = blockIdx.x*256 + threadIdx.x;       // exactly TIN*BB*EDIM threads
  int e = i & 255, b = (i >> 8) & 255, t = i >> 16;
  x_emb[i] = enc_emb[(size_t)input[b*TIN + t]*EDIM + e];
}

// out[t,m,b,h] = sum_l W2[m,l] * in[t,l,b,h]   (in-place safe: each thread owns its 6 slots)
__global__ void mix_kernel(const float* __restrict__ inp, float* __restrict__ outp,
                           const float* __restrict__ W2, int n){
  int i = blockIdx.x*256 + threadIdx.x;
  if (i >= n) return;
  int h = i & 255, b = (i >> 8) & 255, t = i >> 16;
  size_t base = ((size_t)t*6)*BH + (size_t)b*256 + h;
  float v[6];
  #pragma unroll
  for (int l = 0; l < 6; l++) v[l] = inp[base + (size_t)l*BH];
  #pragma unroll
  for (int m = 0; m < 6; m++){
    float s = 0.f;
    #pragma unroll
    for (int l = 0; l < 6; l++) s += W2[m*6+l]*v[l];
    outp[base + (size_t)m*BH] = s;
  }
}

// ---------------- GEMM: C[M,256] = A[M,256] @ W[256,256]^T + bias2d[(row/256)%6][n]
// Full-N blocks (32 rows x 256 cols) => in-place legal (rows partitioned by block).
__global__ __launch_bounds__(256) void gemmN256_kernel(const float* __restrict__ A, float* __restrict__ C,
                                                       const float* __restrict__ W,
                                                       const float* __restrict__ bias2d){
  __shared__ float As[32][33];
  __shared__ float Ws[256][34];
  int tid = threadIdx.x;
  int m_base = blockIdx.x * 32;
  int rg = tid >> 5, cg = tid & 31;
  float acc[4][8];
  #pragma unroll
  for (int i=0;i<4;i++)
    #pragma unroll
    for (int j=0;j<8;j++) acc[i][j]=0.f;
  for (int k0 = 0; k0 < 256; k0 += 32){
    #pragma unroll
    for (int p=0;p<4;p++) As[rg + p*8][cg] = A[(size_t)(m_base + rg + p*8)*256 + k0 + cg];
    #pragma unroll
    for (int p=0;p<32;p++) Ws[rg + p*8][cg] = W[(size_t)(rg + p*8)*256 + k0 + cg];
    __syncthreads();
    #pragma unroll
    for (int kk=0; kk<32; kk++){
      float a[4], w[8];
      #pragma unroll
      for (int i=0;i<4;i++) a[i] = As[rg*4+i][kk];
      #pragma unroll
      for (int j=0;j<8;j++) w[j] = Ws[cg*8+j][kk];
      #pragma unroll
      for (int i=0;i<4;i++)
        #pragma unroll
        for (int j=0;j<8;j++) acc[i][j] += a[i]*w[j];
    }
    __syncthreads();
  }
  #pragma unroll
  for (int i=0;i<4;i++){
    int row = m_base + rg*4 + i;
    int bm = (row >> 8) % 6;
    #pragma unroll
    for (int j=0;j<8;j++)
      C[(size_t)row*256 + cg*8 + j] = acc[i][j] + bias2d[bm*256 + cg*8 + j];
  }
}

// ---------------- generic 2-part GEMM: C[256,N] = A1@W1^T + A2@W2^T + bias, 32x64 tiles
__global__ __launch_bounds__(256) void gemm2_kernel(
    const float* __restrict__ A1, int lda1, int K1, const float* __restrict__ W1, int ldw1,
    const float* __restrict__ A2, int lda2, int K2, const float* __restrict__ W2, int ldw2,
    const float* __restrict__ bias, float* __restrict__ C, int ldc){
  __shared__ float As[32][33];
  __shared__ float Ws[64][33];
  int tid = threadIdx.x;
  int m_base = blockIdx.x*32;
  int n_base = blockIdx.y*64;
  int rg = tid>>5, cg = tid&31;
  float acc[4][2] = {{0.f,0.f},{0.f,0.f},{0.f,0.f},{0.f,0.f}};
  for (int part = 0; part < 2; part++){
    const float* A = part ? A2 : A1;
    const float* W = part ? W2 : W1;
    int lda = part ? lda2 : lda1;
    int ldw = part ? ldw2 : ldw1;
    int K   = part ? K2 : K1;
    for (int k0 = 0; k0 < K; k0 += 32){
      #pragma unroll
      for (int p=0;p<4;p++) As[rg+p*8][cg] = A[(size_t)(m_base+rg+p*8)*lda + k0 + cg];
      #pragma unroll
      for (int p=0;p<8;p++) Ws[rg+p*8][cg] = W[(size_t)(n_base+rg+p*8)*ldw + k0 + cg];
      __syncthreads();
      #pragma unroll
      for (int kk=0;kk<32;kk++){
        float w0 = Ws[cg*2][kk], w1 = Ws[cg*2+1][kk];
        #pragma unroll
        for (int i=0;i<4;i++){
          float av = As[rg*4+i][kk];
          acc[i][0] += av*w0; acc[i][1] += av*w1;
        }
      }
      __syncthreads();
    }
  }
  #pragma unroll
  for (int i=0;i<4;i++){
    int row = m_base + rg*4 + i;
    #pragma unroll
    for (int j=0;j<2;j++){
      int n = n_base + cg*2 + j;
      C[(size_t)row*ldc + n] = acc[i][j] + bias[n];
    }
  }
}

// ---------------- fused LSTM stage: gates GEMM (x-part + h-part) + bias + activations
// grid (8, 32): x -> b-tile (32 b), y -> d = y>>4, h-tile of 16 (all 4 gates).
// N-tile of 64 weight rows = {q*256 + ht*16 + hh : q in 0..3, hh in 0..15}.
__global__ __launch_bounds__(256) void lstm_stage_kernel(
    const float* __restrict__ inp, int lda, int K1,
    const float* __restrict__ Wih_l, const float* __restrict__ Whh_l, const float* __restrict__ bias_l,
    const float* __restrict__ hR, float* __restrict__ hW,
    float* __restrict__ cBuf, float* __restrict__ inp_out,
    float* __restrict__ h_all_t, int l){
  __shared__ float As[32][33];
  __shared__ float Ws[64][33];
  __shared__ float Gt[32][65];
  int tid = threadIdx.x;
  int m_base = blockIdx.x*32;
  int d  = blockIdx.y >> 4;
  int ht = blockIdx.y & 15;
  int idx = 2*l + d;
  const float* Wih  = Wih_l + (size_t)d*GDIM*K1;
  const float* Whh  = Whh_l + (size_t)d*GDIM*HDIM;
  const float* bias = bias_l + d*GDIM;
  const float* A2 = hR + (size_t)idx*BH;
  int rg = tid>>5, cg = tid&31;
  float acc[4][2] = {{0.f,0.f},{0.f,0.f},{0.f,0.f},{0.f,0.f}};
  for (int part = 0; part < 2; part++){
    const float* A = part ? A2 : inp;
    const float* W = part ? Whh : Wih;
    int la = part ? HDIM : lda;
    int lw = part ? HDIM : K1;
    int K  = part ? HDIM : K1;
    for (int k0 = 0; k0 < K; k0 += 32){
      #pragma unroll
      for (int p=0;p<4;p++) As[rg+p*8][cg] = A[(size_t)(m_base+rg+p*8)*la + k0 + cg];
      #pragma unroll
      for (int p=0;p<8;p++){
        int row = rg + p*8;
        int wrow = (row >> 4)*256 + ht*16 + (row & 15);
        Ws[row][cg] = W[(size_t)wrow*lw + k0 + cg];
      }
      __syncthreads();
      #pragma unroll
      for (int kk=0;kk<32;kk++){
        float w0 = Ws[cg*2][kk], w1 = Ws[cg*2+1][kk];
        #pragma unroll
        for (int i=0;i<4;i++){
          float av = As[rg*4+i][kk];
          acc[i][0] += av*w0; acc[i][1] += av*w1;
        }
      }
      __syncthreads();
    }
  }
  #pragma unroll
  for (int i=0;i<4;i++){ Gt[rg*4+i][cg*2] = acc[i][0]; Gt[rg*4+i][cg*2+1] = acc[i][1]; }
  __syncthreads();
  #pragma unroll
  for (int it = 0; it < 2; it++){
    int id = tid + it*256;
    int bbi = id >> 4, hh = id & 15;
    int b = m_base + bbi, h = ht*16 + hh;
    float iv = Gt[bbi][hh]      + bias[h];
    float fv = Gt[bbi][16+hh]   + bias[256+h];
    float gv = Gt[bbi][32+hh]   + bias[512+h];
    float ov = Gt[bbi][48+hh]   + bias[768+h];
    size_t off = (size_t)idx*BH + (size_t)b*HDIM + h;
    float cold = cBuf[off];
    float cc = sigmf(fv)*cold + sigmf(iv)*tanhf(gv);
    float hv = sigmf(ov)*tanhf(cc);
    cBuf[off] = cc;
    hW[off] = hv;
    inp_out[(size_t)b*(2*HDIM) + (size_t)d*HDIM + h] = hv;
    if (h_all_t) h_all_t[off] = hv;
  }
}

// ---------------- attention: ctx[b,h] = mean_d sum_t softmax_t(h*eo)*eo
__global__ void attn_ctx_kernel(const float* __restrict__ hR, const float* __restrict__ eo,
                                float* __restrict__ ctx, const int* __restrict__ tf,
                                float* __restrict__ attn_out, int step){
  int i = blockIdx.x*256 + threadIdx.x;   // BH threads
  int hc = i & 255, b = i >> 8;
  bool wa = (tf[0] == 0);
  float acc = 0.f;
  for (int d = 0; d < DD; d++){
    float hv = hR[(size_t)d*BH + (size_t)b*256 + hc];
    float ev[TIN];
    float mx = -1e30f;
    #pragma unroll
    for (int t = 0; t < TIN; t++){
      ev[t] = eo[(((size_t)t*DD + d)*BB + b)*256 + hc];
      mx = fmaxf(mx, hv*ev[t]);
    }
    float se = 0.f;
    #pragma unroll
    for (int t = 0; t < TIN; t++) se += expf(hv*ev[t] - mx);
    float inv = 1.f/se;
    #pragma unroll
    for (int t = 0; t < TIN; t++){
      float aw = expf(hv*ev[t] - mx)*inv;
      acc += aw*ev[t];
      if (wa) atomicAdd(&attn_out[(((size_t)(step+1)*TIN + t)*DD + d)*BB + b], aw);
    }
  }
  ctx[i] = acc * (1.f/6.f);
}

// ---------------- token select + decoder embedding gather (one block per b)
__global__ void tok_emb_kernel(const int* __restrict__ tf, const int* __restrict__ target,
                               const float* __restrict__ pred, const float* __restrict__ dec_emb,
                               float* __restrict__ emb, int step){
  __shared__ int sTok;
  int b = blockIdx.x, tid = threadIdx.x;
  if (tid == 0){
    int tok;
    if (tf[0]) tok = target[b*TOUT + step];
    else if (step == 0) tok = 1;
    else {
      const float* lg = pred + ((size_t)step*BB + b)*VDEC;
      tok = 0; float bv = lg[0];
      for (int v = 1; v < VDEC; v++){ float x = lg[v]; if (x > bv){ bv = x; tok = v; } }
    }
    sTok = tok;
  }
  __syncthreads();
  emb[(size_t)b*EDIM + tid] = dec_emb[(size_t)sTok*EDIM + tid];
}

// ---------------- fc head: logits[b,v] = top[b,:512] . fc_W[v,:] + fc_b[v]
__global__ void fc_kernel(const float* __restrict__ top, const float* __restrict__ fc_W,
                          const float* __restrict__ fc_b, float* __restrict__ outp, int step){
  __shared__ float s[512];
  int b = blockIdx.x, tid = threadIdx.x;
  s[tid]       = top[(size_t)b*512 + tid];
  s[tid + 256] = top[(size_t)b*512 + 256 + tid];
  __syncthreads();
  if (tid < VDEC){
    float a = fc_b[tid];
    for (int k = 0; k < 512; k++) a += s[k]*fc_W[(size_t)tid*512 + k];
    outp[((size_t)(step+1)*BB + b)*VDEC + tid] = a;
  }
}

// =====================================================================

extern "C" void kernel_launch(void* const* d_in, const int* in_sizes, int n_in,
                              void* d_out, int out_size, void* d_ws, size_t ws_size,
                              hipStream_t stream){
  const int*   input    = (const int*)d_in[0];
  const int*   target   = (const int*)d_in[1];
  const int*   tf       = (const int*)d_in[2];
  const float* enc_emb  = (const float*)d_in[3];
  const float* dec_emb  = (const float*)d_in[4];
  const float* enc_Wih0 = (const float*)d_in[5];
  const float* enc_Wih1 = (const float*)d_in[6];
  const float* enc_Whh  = (const float*)d_in[7];
  const float* enc_b    = (const float*)d_in[8];
  const float* dec_Wih0 = (const float*)d_in[9];
  const float* dec_Wih1 = (const float*)d_in[10];
  const float* dec_Whh  = (const float*)d_in[11];
  const float* dec_b    = (const float*)d_in[12];
  const float* lin_h_W1 = (const float*)d_in[13];
  const float* lin_h_b1 = (const float*)d_in[14];
  const float* lin_h_W2 = (const float*)d_in[15];
  const float* lin_h_b2 = (const float*)d_in[16];
  const float* lin_c_W1 = (const float*)d_in[17];
  const float* lin_c_b1 = (const float*)d_in[18];
  const float* lin_c_W2 = (const float*)d_in[19];
  const float* lin_c_b2 = (const float*)d_in[20];
  const float* lin_a_W1 = (const float*)d_in[21];
  const float* lin_a_b1 = (const float*)d_in[22];
  const float* lin_a_W2 = (const float*)d_in[23];
  const float* lin_a_b2 = (const float*)d_in[24];
  const float* attn_W   = (const float*)d_in[25];
  const float* attn_b   = (const float*)d_in[26];
  const float* fc_W     = (const float*)d_in[27];
  const float* fc_b     = (const float*)d_in[28];
  float* out = (float*)d_out;

  float* ws = (float*)d_ws;
  size_t o = 0;
  float* x_emb  = ws + o; o += (size_t)TIN*BB*EDIM;   // [Tin,B,E]
  float* h_all  = ws + o; o += (size_t)TIN*DD*BH;     // [Tin,D,B,H] -> becomes encoder_outputs
  float* enc_hA = ws + o; o += (size_t)DD*BH;         // (hA and c adjacent: zeroed together)
  float* enc_c  = ws + o; o += (size_t)DD*BH;
  float* enc_hB = ws + o; o += (size_t)DD*BH;
  float* dec_hA = ws + o; o += (size_t)DD*BH;
  float* dec_hB = ws + o; o += (size_t)DD*BH;
  float* dec_c  = ws + o; o += (size_t)DD*BH;
  float* tmp6   = ws + o; o += (size_t)DD*BH;
  float* bufA   = ws + o; o += (size_t)BB*2*HDIM;
  float* bufB   = ws + o; o += (size_t)BB*2*HDIM;
  float* emb    = ws + o; o += (size_t)BB*EDIM;
  float* ctx    = ws + o; o += (size_t)BB*EDIM;
  float* xw     = ws + o; o += (size_t)BB*EDIM;
  float* bias2d = ws + o; o += 3*6*256;

  const int outn = TOUT*BB*VDEC + TOUT*TIN*DD*BB;
  init_out_kernel<<<(outn+255)/256, 256, 0, stream>>>(out, outn);
  fill_zero_kernel<<<(2*DD*BH)/256, 256, 0, stream>>>(enc_hA, 2*DD*BH);
  bias2d_kernel<<<1, 256, 0, stream>>>(lin_a_W2, lin_a_b1, lin_a_b2,
                                       lin_h_W2, lin_h_b1, lin_h_b2,
                                       lin_c_W2, lin_c_b1, lin_c_b2, bias2d);
  embed_enc_kernel<<<(TIN*BB*EDIM)/256, 256, 0, stream>>>(input, enc_emb, x_emb);

  dim3 sgrid(8, 32);
  // -------- encoder --------
  for (int t = 0; t < TIN; t++){
    const float* hR = (t & 1) ? enc_hB : enc_hA;
    float*       hW = (t & 1) ? enc_hA : enc_hB;
    float* hat = h_all + (size_t)t*DD*BH;
    lstm_stage_kernel<<<sgrid,256,0,stream>>>(x_emb + (size_t)t*BB*EDIM, EDIM, EDIM,
        enc_Wih0, enc_Whh, enc_b, hR, hW, enc_c, bufA, hat, 0);
    lstm_stage_kernel<<<sgrid,256,0,stream>>>(bufA, 512, 512,
        enc_Wih1, enc_Whh + 2*GDIM*HDIM, enc_b + 2*GDIM, hR, hW, enc_c, bufB, hat, 1);
    lstm_stage_kernel<<<sgrid,256,0,stream>>>(bufB, 512, 512,
        enc_Wih1 + (size_t)2*GDIM*512, enc_Whh + 4*GDIM*HDIM, enc_b + 4*GDIM,
        hR, hW, enc_c, bufA, hat, 2);
  }
  // -------- attention projection of all encoder states (mix-first, then in-place GEMM) --------
  mix_kernel<<<(TIN*BH)/256, 256, 0, stream>>>(h_all, h_all, lin_a_W2, TIN*BH);
  gemmN256_kernel<<<(TIN*DD*BB)/32, 256, 0, stream>>>(h_all, h_all, lin_a_W1, bias2d + 0);
  // -------- encoder->decoder state bridge (final h written into enc_hA at t=31) --------
  mix_kernel<<<BH/256, 256, 0, stream>>>(enc_hA, tmp6, lin_h_W2, BH);
  gemmN256_kernel<<<(DD*BB)/32, 256, 0, stream>>>(tmp6, dec_hA, lin_h_W1, bias2d + 1536);
  mix_kernel<<<BH/256, 256, 0, stream>>>(enc_c, tmp6, lin_c_W2, BH);
  gemmN256_kernel<<<(DD*BB)/32, 256, 0, stream>>>(tmp6, dec_c, lin_c_W1, bias2d + 3072);

  // -------- decoder --------
  float* attn_out = out + (size_t)TOUT*BB*VDEC;
  for (int i = 0; i < TOUT-1; i++){
    const float* hR = (i & 1) ? dec_hB : dec_hA;
    float*       hW = (i & 1) ? dec_hA : dec_hB;
    tok_emb_kernel<<<BB, 256, 0, stream>>>(tf, target, out, dec_emb, emb, i);
    attn_ctx_kernel<<<BH/256, 256, 0, stream>>>(hR, h_all, ctx, tf, attn_out, i);
    gemm2_kernel<<<dim3(8,4),256,0,stream>>>(emb, EDIM, EDIM, attn_W, 512,
                                             ctx, HDIM, HDIM, attn_W + 256, 512,
                                             attn_b, xw, EDIM);
    lstm_stage_kernel<<<sgrid,256,0,stream>>>(xw, EDIM, EDIM,
        dec_Wih0, dec_Whh, dec_b, hR, hW, dec_c, bufA, nullptr, 0);
    lstm_stage_kernel<<<sgrid,256,0,stream>>>(bufA, 512, 512,
        dec_Wih1, dec_Whh + 2*GDIM*HDIM, dec_b + 2*GDIM, hR, hW, dec_c, bufB, nullptr, 1);
    lstm_stage_kernel<<<sgrid,256,0,stream>>>(bufB, 512, 512,
        dec_Wih1 + (size_t)2*GDIM*512, dec_Whh + 4*GDIM*HDIM, dec_b + 4*GDIM,
        hR, hW, dec_c, bufA, nullptr, 2);
    fc_kernel<<<BB, 256, 0, stream>>>(bufA, fc_W, fc_b, out, i);
  }
}

// Round 2
// 3463.194 us; speedup vs baseline: 2.5215x; 2.5215x over previous
//
#include <hip/hip_runtime.h>
#include <math.h>

#define BB 256
#define TIN 32
#define TOUT 29
#define VDEC 72
#define EDIM 256
#define HDIM 256
#define DD 6
#define BH (BB*HDIM)

typedef unsigned short u16;
typedef unsigned int u32;
typedef __bf16 bf16x8 __attribute__((ext_vector_type(8)));
typedef float f32x4 __attribute__((ext_vector_type(4)));
typedef u16 u16x8 __attribute__((ext_vector_type(8)));

__device__ __forceinline__ float sigmf(float x){ return 1.0f/(1.0f+expf(-x)); }
__device__ __forceinline__ u16 f2bf(float f){
  u32 u = __builtin_bit_cast(u32, f);
  u32 r = (u + 0x7fffu + ((u>>16)&1u)) >> 16;   // RNE; inputs finite
  return (u16)r;
}
__device__ __forceinline__ float bf2f(u16 s){
  u32 u = ((u32)s)<<16; return __builtin_bit_cast(float, u);
}
__device__ __forceinline__ bf16x8 ldbf8(const u16* p){
  u16x8 t = *(const u16x8*)p; return __builtin_bit_cast(bf16x8, t);
}
__device__ __forceinline__ f32x4 mfma16(bf16x8 a, bf16x8 b, f32x4 c){
  return __builtin_amdgcn_mfma_f32_16x16x32_bf16(a, b, c, 0, 0, 0);
}

// ---------------- init ----------------
__global__ void fill_zero_u32(u32* __restrict__ p, int n){
  int i = blockIdx.x*256 + threadIdx.x;
  if (i < n) p[i] = 0u;
}

__global__ void init_out_kernel(float* __restrict__ out, int n){
  int i = blockIdx.x*256 + threadIdx.x;
  if (i >= n) return;
  float v = 0.0f;
  if (i < BB*VDEC && (i % VDEC) == 1) v = 1.0f;   // pred0 one-hot
  out[i] = v;
}

// bias2d[p][m][g] = (sum_l W2[m,l]) * b1[g] + b2[m]   (p: 0=a, 1=h, 2=c)
__global__ void bias2d_kernel(const float* __restrict__ W2a, const float* __restrict__ b1a, const float* __restrict__ b2a,
                              const float* __restrict__ W2h, const float* __restrict__ b1h, const float* __restrict__ b2h,
                              const float* __restrict__ W2c, const float* __restrict__ b1c, const float* __restrict__ b2c,
                              float* __restrict__ outp){
  int g = threadIdx.x;
  const float* W2[3] = {W2a, W2h, W2c};
  const float* b1[3] = {b1a, b1h, b1c};
  const float* b2[3] = {b2a, b2h, b2c};
  for (int p = 0; p < 3; p++)
    for (int m = 0; m < 6; m++){
      float s = 0.f;
      for (int l = 0; l < 6; l++) s += W2[p][m*6+l];
      outp[p*1536 + m*256 + g] = s * b1[p][g] + b2[p][m];
    }
}

__global__ void embed_enc_kernel(const int* __restrict__ input, const float* __restrict__ enc_emb,
                                 u16* __restrict__ x_emb){
  int i = blockIdx.x*256 + threadIdx.x;       // TIN*BB*EDIM threads
  int e = i & 255, b = (i >> 8) & 255, t = i >> 16;
  x_emb[i] = f2bf(enc_emb[(size_t)input[b*TIN + t]*EDIM + e]);
}

// pack fp32 weights -> bf16, row-permuted so each stage block's 64 rows are contiguous.
// dst row' = (d*16+ht)*64 + q*16 + hh  <->  src gate row g = q*256 + ht*16 + hh of dir d.
__global__ void pack_w_kernel(const float* __restrict__ Wih, const float* __restrict__ Whh,
                              u16* __restrict__ dst, int K1, int K, int permute){
  int k = blockIdx.x*256 + threadIdx.x;
  int row = blockIdx.y;
  int d = row >> 10, rr = row & 1023;
  int g;
  if (permute){
    int ht = rr >> 6, r = rr & 63;
    g = (r>>4)*256 + ht*16 + (r&15);
  } else g = rr;
  float v;
  if (k < K1) v = Wih[((size_t)d*1024 + g)*K1 + k];
  else        v = Whh[((size_t)d*1024 + g)*256 + (k - K1)];
  dst[(size_t)row*K + k] = f2bf(v);
}

// out[t,m,b,h] = sum_l W2[m,l] * in[t,l,b,h]  (fp32, in-place safe)
__global__ void mix_kernel(const float* __restrict__ inp, float* __restrict__ outp,
                           const float* __restrict__ W2, int n){
  int i = blockIdx.x*256 + threadIdx.x;
  if (i >= n) return;
  int h = i & 255, b = (i >> 8) & 255, t = i >> 16;
  size_t base = ((size_t)t*6)*BH + (size_t)b*256 + h;
  float v[6];
  #pragma unroll
  for (int l = 0; l < 6; l++) v[l] = inp[base + (size_t)l*BH];
  #pragma unroll
  for (int m = 0; m < 6; m++){
    float s = 0.f;
    #pragma unroll
    for (int l = 0; l < 6; l++) s += W2[m*6+l]*v[l];
    outp[base + (size_t)m*BH] = s;
  }
}

// C[M,256] = A[M,256] @ W[256,256]^T + bias2d[(row/256)%6][n]  (fp32, full-N blocks)
__global__ __launch_bounds__(256) void gemmN256_kernel(const float* __restrict__ A, float* __restrict__ C,
                                                       const float* __restrict__ W,
                                                       const float* __restrict__ bias2d,
                                                       u16* __restrict__ Cbf){
  __shared__ float As[32][33];
  __shared__ float Ws[256][34];
  int tid = threadIdx.x;
  int m_base = blockIdx.x * 32;
  int rg = tid >> 5, cg = tid & 31;
  float acc[4][8];
  #pragma unroll
  for (int i=0;i<4;i++)
    #pragma unroll
    for (int j=0;j<8;j++) acc[i][j]=0.f;
  for (int k0 = 0; k0 < 256; k0 += 32){
    #pragma unroll
    for (int p=0;p<4;p++) As[rg + p*8][cg] = A[(size_t)(m_base + rg + p*8)*256 + k0 + cg];
    #pragma unroll
    for (int p=0;p<32;p++) Ws[rg + p*8][cg] = W[(size_t)(rg + p*8)*256 + k0 + cg];
    __syncthreads();
    #pragma unroll
    for (int kk=0; kk<32; kk++){
      float a[4], w[8];
      #pragma unroll
      for (int i=0;i<4;i++) a[i] = As[rg*4+i][kk];
      #pragma unroll
      for (int j=0;j<8;j++) w[j] = Ws[cg*8+j][kk];
      #pragma unroll
      for (int i=0;i<4;i++)
        #pragma unroll
        for (int j=0;j<8;j++) acc[i][j] += a[i]*w[j];
    }
    __syncthreads();
  }
  #pragma unroll
  for (int i=0;i<4;i++){
    int row = m_base + rg*4 + i;
    int bm = (row >> 8) % 6;
    #pragma unroll
    for (int j=0;j<8;j++){
      float v = acc[i][j] + bias2d[bm*256 + cg*8 + j];
      C[(size_t)row*256 + cg*8 + j] = v;
      if (Cbf) Cbf[(size_t)row*256 + cg*8 + j] = f2bf(v);
    }
  }
}

// ---------------- fused LSTM stage, bf16 MFMA ----------------
// grid (8, 32): x -> 32-batch tile; y -> d = y>>4, ht = y&15.
// Block's 64 weight rows (packed-contiguous) = {q*16+hh} <-> gates q at h = ht*16+hh.
__global__ __launch_bounds__(256) void lstm_stage_mfma(
    const u16* __restrict__ inp, int lda, int K1,
    const u16* __restrict__ Wpk,
    const float* __restrict__ bias_l,
    const u16* __restrict__ hR, u16* __restrict__ hW,
    float* __restrict__ cBuf, u16* __restrict__ inp_out,
    float* __restrict__ h_all_t, int l){
  __shared__ __align__(16) u16 As[32][72];
  __shared__ __align__(16) u16 Ws[64][72];
  __shared__ float Gt[4][32][17];
  int tid = threadIdx.x;
  int m_base = blockIdx.x*32;
  int d = blockIdx.y >> 4, ht = blockIdx.y & 15;
  int idx = 2*l + d;
  int K = K1 + 256;
  const u16* Wblk = Wpk + (size_t)((d*16+ht)*64)*K;
  const u16* A2 = hR + (size_t)idx*BH;
  int q = tid >> 6, lane = tid & 63;
  int ar = tid >> 3, kp = (tid & 7)*8;
  f32x4 acc0 = {0.f,0.f,0.f,0.f}, acc1 = {0.f,0.f,0.f,0.f};
  for (int c0 = 0; c0 < K; c0 += 64){
    int col = c0 + kp;
    const u16* ap = (col < K1) ? inp + (size_t)(m_base+ar)*lda + col
                               : A2  + (size_t)(m_base+ar)*HDIM + (col - K1);
    uint4 av  = *(const uint4*)ap;
    uint4 wv0 = *(const uint4*)(Wblk + (size_t)ar*K + col);
    uint4 wv1 = *(const uint4*)(Wblk + (size_t)(ar+32)*K + col);
    __syncthreads();
    *(uint4*)&As[ar][kp] = av;
    *(uint4*)&Ws[ar][kp] = wv0;
    *(uint4*)&Ws[ar+32][kp] = wv1;
    __syncthreads();
    #pragma unroll
    for (int kh = 0; kh < 2; kh++){
      int kb = kh*32 + (lane>>4)*8;
      bf16x8 a0 = ldbf8(&As[lane & 15][kb]);
      bf16x8 a1 = ldbf8(&As[16 + (lane & 15)][kb]);
      bf16x8 bq = ldbf8(&Ws[q*16 + (lane & 15)][kb]);
      acc0 = mfma16(a0, bq, acc0);
      acc1 = mfma16(a1, bq, acc1);
    }
  }
  int hh = lane & 15, rq = lane >> 4;
  #pragma unroll
  for (int r = 0; r < 4; r++){
    Gt[q][rq*4 + r][hh]      = acc0[r];
    Gt[q][16 + rq*4 + r][hh] = acc1[r];
  }
  __syncthreads();
  const float* bias = bias_l + d*1024;
  #pragma unroll
  for (int it = 0; it < 2; it++){
    int id = tid + it*256;
    int bb = id >> 4, h2 = id & 15;
    int b = m_base + bb, h = ht*16 + h2;
    float iv = Gt[0][bb][h2] + bias[h];
    float fv = Gt[1][bb][h2] + bias[256 + h];
    float gv = Gt[2][bb][h2] + bias[512 + h];
    float ov = Gt[3][bb][h2] + bias[768 + h];
    size_t off = (size_t)idx*BH + (size_t)b*HDIM + h;
    float cold = cBuf[off];
    float cc = sigmf(fv)*cold + sigmf(iv)*tanhf(gv);
    float hv = sigmf(ov)*tanhf(cc);
    cBuf[off] = cc;
    u16 hb = f2bf(hv);
    hW[off] = hb;
    inp_out[(size_t)b*512 + d*HDIM + h] = hb;
    if (h_all_t) h_all_t[off] = hv;
  }
}

// ---------------- xw = [emb, ctx] @ attn_W^T + attn_b  (bf16 MFMA), grid (8,4)
__global__ __launch_bounds__(256) void xw_mfma(
    const u16* __restrict__ emb, const u16* __restrict__ ctx,
    const u16* __restrict__ Wpk, const float* __restrict__ bias,
    u16* __restrict__ xw){
  __shared__ __align__(16) u16 As[32][72];
  __shared__ __align__(16) u16 Ws[64][72];
  int tid = threadIdx.x;
  int m_base = blockIdx.x*32;
  int n_base = blockIdx.y*64;
  int q = tid >> 6, lane = tid & 63;
  int ar = tid >> 3, kp = (tid & 7)*8;
  const u16* Wblk = Wpk + (size_t)n_base*512;
  f32x4 acc0 = {0.f,0.f,0.f,0.f}, acc1 = {0.f,0.f,0.f,0.f};
  for (int c0 = 0; c0 < 512; c0 += 64){
    int col = c0 + kp;
    const u16* ap = (col < 256) ? emb + (size_t)(m_base+ar)*256 + col
                                : ctx + (size_t)(m_base+ar)*256 + (col - 256);
    uint4 av  = *(const uint4*)ap;
    uint4 wv0 = *(const uint4*)(Wblk + (size_t)ar*512 + col);
    uint4 wv1 = *(const uint4*)(Wblk + (size_t)(ar+32)*512 + col);
    __syncthreads();
    *(uint4*)&As[ar][kp] = av;
    *(uint4*)&Ws[ar][kp] = wv0;
    *(uint4*)&Ws[ar+32][kp] = wv1;
    __syncthreads();
    #pragma unroll
    for (int kh = 0; kh < 2; kh++){
      int kb = kh*32 + (lane>>4)*8;
      bf16x8 a0 = ldbf8(&As[lane & 15][kb]);
      bf16x8 a1 = ldbf8(&As[16 + (lane & 15)][kb]);
      bf16x8 bq = ldbf8(&Ws[q*16 + (lane & 15)][kb]);
      acc0 = mfma16(a0, bq, acc0);
      acc1 = mfma16(a1, bq, acc1);
    }
  }
  int hh = lane & 15, rq = lane >> 4;
  int n = n_base + q*16 + hh;
  float bv = bias[n];
  #pragma unroll
  for (int r = 0; r < 4; r++){
    xw[(size_t)(m_base + rq*4 + r)*256 + n]      = f2bf(acc0[r] + bv);
    xw[(size_t)(m_base + 16 + rq*4 + r)*256 + n] = f2bf(acc1[r] + bv);
  }
}

// ---------------- attention ctx + token embed (fused), grid 320 ----------------
__global__ void attn_tok_kernel(const u16* __restrict__ hR, const float* __restrict__ eo,
                                u16* __restrict__ ctx, const int* __restrict__ tf,
                                float* __restrict__ attn_out, int step,
                                const int* __restrict__ target, const float* __restrict__ pred,
                                const float* __restrict__ dec_emb, u16* __restrict__ emb){
  int blk = blockIdx.x, tid = threadIdx.x;
  if (blk < 256){
    int i = blk*256 + tid;
    int hc = i & 255, b = i >> 8;
    bool wa = (tf[0] == 0);
    float acc = 0.f;
    for (int d = 0; d < DD; d++){
      float hv = bf2f(hR[(size_t)d*BH + (size_t)b*256 + hc]);
      const float* ep = eo + (size_t)d*BH + (size_t)b*256 + hc;
      float se = 0.f, ac = 0.f;
      for (int t = 0; t < TIN; t++){
        float ev = ep[(size_t)t*(DD*BH)];
        float e = expf(hv*ev);          // bounded args; softmax ratio exact
        se += e; ac += e*ev;
      }
      acc += ac/se;
      if (wa){
        float inv = 1.f/se;
        for (int t = 0; t < TIN; t++){
          float ev = ep[(size_t)t*(DD*BH)];
          atomicAdd(&attn_out[(((size_t)(step+1)*TIN + t)*DD + d)*BB + b], expf(hv*ev)*inv);
        }
      }
    }
    ctx[i] = f2bf(acc*(1.0f/6.0f));
  } else {
    int j = (blk - 256)*256 + tid;      // 16384 = B * 64 four-elem units
    int b = j >> 6, e4 = (j & 63)*4;
    int tok;
    if (tf[0]) tok = target[b*TOUT + step];
    else if (step == 0) tok = 1;
    else {
      const float* lg = pred + ((size_t)step*BB + b)*VDEC;
      tok = 0; float bv = lg[0];
      for (int v = 1; v < VDEC; v++){ float x = lg[v]; if (x > bv){ bv = x; tok = v; } }
    }
    #pragma unroll
    for (int r = 0; r < 4; r++)
      emb[(size_t)b*EDIM + e4 + r] = f2bf(dec_emb[(size_t)tok*EDIM + e4 + r]);
  }
}

// ---------------- fc head ----------------
__global__ void fc_kernel(const u16* __restrict__ top, const float* __restrict__ fc_W,
                          const float* __restrict__ fc_b, float* __restrict__ outp, int step){
  __shared__ float s[512];
  int b = blockIdx.x, tid = threadIdx.x;
  s[tid]       = bf2f(top[(size_t)b*512 + tid]);
  s[tid + 256] = bf2f(top[(size_t)b*512 + 256 + tid]);
  __syncthreads();
  if (tid < VDEC){
    float a = fc_b[tid];
    for (int k = 0; k < 512; k++) a += s[k]*fc_W[(size_t)tid*512 + k];
    outp[((size_t)(step+1)*BB + b)*VDEC + tid] = a;
  }
}

// =====================================================================

extern "C" void kernel_launch(void* const* d_in, const int* in_sizes, int n_in,
                              void* d_out, int out_size, void* d_ws, size_t ws_size,
                              hipStream_t stream){
  (void)in_sizes; (void)n_in; (void)out_size; (void)ws_size;
  const int*   input    = (const int*)d_in[0];
  const int*   target   = (const int*)d_in[1];
  const int*   tf       = (const int*)d_in[2];
  const float* enc_emb  = (const float*)d_in[3];
  const float* dec_emb  = (const float*)d_in[4];
  const float* enc_Wih0 = (const float*)d_in[5];
  const float* enc_Wih1 = (const float*)d_in[6];
  const float* enc_Whh  = (const float*)d_in[7];
  const float* enc_b    = (const float*)d_in[8];
  const float* dec_Wih0 = (const float*)d_in[9];
  const float* dec_Wih1 = (const float*)d_in[10];
  const float* dec_Whh  = (const float*)d_in[11];
  const float* dec_b    = (const float*)d_in[12];
  const float* lin_h_W1 = (const float*)d_in[13];
  const float* lin_h_b1 = (const float*)d_in[14];
  const float* lin_h_W2 = (const float*)d_in[15];
  const float* lin_h_b2 = (const float*)d_in[16];
  const float* lin_c_W1 = (const float*)d_in[17];
  const float* lin_c_b1 = (const float*)d_in[18];
  const float* lin_c_W2 = (const float*)d_in[19];
  const float* lin_c_b2 = (const float*)d_in[20];
  const float* lin_a_W1 = (const float*)d_in[21];
  const float* lin_a_b1 = (const float*)d_in[22];
  const float* lin_a_W2 = (const float*)d_in[23];
  const float* lin_a_b2 = (const float*)d_in[24];
  const float* attn_W   = (const float*)d_in[25];
  const float* attn_b   = (const float*)d_in[26];
  const float* fc_W     = (const float*)d_in[27];
  const float* fc_b     = (const float*)d_in[28];
  float* out = (float*)d_out;

  char* base = (char*)d_ws;
  size_t off = 0;
  auto alloc = [&](size_t bytes)->char*{
    char* p = base + off; off += (bytes + 255) & ~(size_t)255; return p;
  };
  float* h_all  = (float*)alloc(sizeof(float)*(size_t)TIN*DD*BH);
  float* tmp6   = (float*)alloc(sizeof(float)*(size_t)DD*BH);
  float* dec_c  = (float*)alloc(sizeof(float)*(size_t)DD*BH);
  float* bias2d = (float*)alloc(sizeof(float)*3*6*256);
  // zero block: enc_hA (bf16) + enc_c (fp32), contiguous
  u16*   enc_hA = (u16*)alloc(sizeof(u16)*(size_t)DD*BH + sizeof(float)*(size_t)DD*BH);
  float* enc_c  = (float*)(enc_hA + (size_t)DD*BH);
  u16* enc_hB = (u16*)alloc(sizeof(u16)*(size_t)DD*BH);
  u16* dec_hA = (u16*)alloc(sizeof(u16)*(size_t)DD*BH);
  u16* dec_hB = (u16*)alloc(sizeof(u16)*(size_t)DD*BH);
  u16* x_emb  = (u16*)alloc(sizeof(u16)*(size_t)TIN*BB*EDIM);
  u16* bufA   = (u16*)alloc(sizeof(u16)*(size_t)BB*512);
  u16* bufB   = (u16*)alloc(sizeof(u16)*(size_t)BB*512);
  u16* emb    = (u16*)alloc(sizeof(u16)*(size_t)BB*256);
  u16* ctxb   = (u16*)alloc(sizeof(u16)*(size_t)BB*256);
  u16* xw     = (u16*)alloc(sizeof(u16)*(size_t)BB*256);
  u16* wp_e0  = (u16*)alloc(sizeof(u16)*(size_t)2048*512);
  u16* wp_e1  = (u16*)alloc(sizeof(u16)*(size_t)2048*768);
  u16* wp_e2  = (u16*)alloc(sizeof(u16)*(size_t)2048*768);
  u16* wp_d0  = (u16*)alloc(sizeof(u16)*(size_t)2048*512);
  u16* wp_d1  = (u16*)alloc(sizeof(u16)*(size_t)2048*768);
  u16* wp_d2  = (u16*)alloc(sizeof(u16)*(size_t)2048*768);
  u16* wp_at  = (u16*)alloc(sizeof(u16)*(size_t)256*512);

  const int outn = TOUT*BB*VDEC + TOUT*TIN*DD*BB;
  init_out_kernel<<<(outn+255)/256, 256, 0, stream>>>(out, outn);
  fill_zero_u32<<<(DD*BH*6/4 + 255)/256, 256, 0, stream>>>((u32*)enc_hA, DD*BH*6/4);
  bias2d_kernel<<<1, 256, 0, stream>>>(lin_a_W2, lin_a_b1, lin_a_b2,
                                       lin_h_W2, lin_h_b1, lin_h_b2,
                                       lin_c_W2, lin_c_b1, lin_c_b2, bias2d);
  embed_enc_kernel<<<(TIN*BB*EDIM)/256, 256, 0, stream>>>(input, enc_emb, x_emb);
  pack_w_kernel<<<dim3(2,2048), 256, 0, stream>>>(enc_Wih0, enc_Whh,                       wp_e0, 256, 512, 1);
  pack_w_kernel<<<dim3(3,2048), 256, 0, stream>>>(enc_Wih1, enc_Whh + 2*1024*256,          wp_e1, 512, 768, 1);
  pack_w_kernel<<<dim3(3,2048), 256, 0, stream>>>(enc_Wih1 + (size_t)2*1024*512, enc_Whh + 4*1024*256, wp_e2, 512, 768, 1);
  pack_w_kernel<<<dim3(2,2048), 256, 0, stream>>>(dec_Wih0, dec_Whh,                       wp_d0, 256, 512, 1);
  pack_w_kernel<<<dim3(3,2048), 256, 0, stream>>>(dec_Wih1, dec_Whh + 2*1024*256,          wp_d1, 512, 768, 1);
  pack_w_kernel<<<dim3(3,2048), 256, 0, stream>>>(dec_Wih1 + (size_t)2*1024*512, dec_Whh + 4*1024*256, wp_d2, 512, 768, 1);
  pack_w_kernel<<<dim3(2,256),  256, 0, stream>>>(attn_W, attn_W /*unused*/,               wp_at, 512, 512, 0);

  dim3 sgrid(8, 32);
  // -------- encoder --------
  for (int t = 0; t < TIN; t++){
    const u16* hRb = (t & 1) ? enc_hB : enc_hA;
    u16*       hWb = (t & 1) ? enc_hA : enc_hB;
    float* hat = h_all + (size_t)t*DD*BH;
    lstm_stage_mfma<<<sgrid,256,0,stream>>>(x_emb + (size_t)t*BB*EDIM, 256, 256, wp_e0,
        enc_b,        hRb, hWb, enc_c, bufA, hat, 0);
    lstm_stage_mfma<<<sgrid,256,0,stream>>>(bufA, 512, 512, wp_e1,
        enc_b + 2048, hRb, hWb, enc_c, bufB, hat, 1);
    lstm_stage_mfma<<<sgrid,256,0,stream>>>(bufB, 512, 512, wp_e2,
        enc_b + 4096, hRb, hWb, enc_c, bufA, hat, 2);
  }
  // -------- bridges FIRST (need un-projected h_all[t=31]), then in-place a-projection --------
  mix_kernel<<<BH/256, 256, 0, stream>>>(h_all + (size_t)31*DD*BH, tmp6, lin_h_W2, BH);
  gemmN256_kernel<<<(DD*BB)/32, 256, 0, stream>>>(tmp6, tmp6, lin_h_W1, bias2d + 1536, dec_hA);
  mix_kernel<<<BH/256, 256, 0, stream>>>(enc_c, tmp6, lin_c_W2, BH);
  gemmN256_kernel<<<(DD*BB)/32, 256, 0, stream>>>(tmp6, dec_c, lin_c_W1, bias2d + 3072, nullptr);
  mix_kernel<<<(TIN*BH)/256, 256, 0, stream>>>(h_all, h_all, lin_a_W2, TIN*BH);
  gemmN256_kernel<<<(TIN*DD*BB)/32, 256, 0, stream>>>(h_all, h_all, lin_a_W1, bias2d, nullptr);

  // -------- decoder --------
  float* attn_out = out + (size_t)TOUT*BB*VDEC;
  for (int i = 0; i < TOUT-1; i++){
    const u16* hRb = (i & 1) ? dec_hB : dec_hA;
    u16*       hWb = (i & 1) ? dec_hA : dec_hB;
    attn_tok_kernel<<<320, 256, 0, stream>>>(hRb, h_all, ctxb, tf, attn_out, i,
                                             target, out, dec_emb, emb);
    xw_mfma<<<dim3(8,4), 256, 0, stream>>>(emb, ctxb, wp_at, attn_b, xw);
    lstm_stage_mfma<<<sgrid,256,0,stream>>>(xw, 256, 256, wp_d0,
        dec_b,        hRb, hWb, dec_c, bufA, nullptr, 0);
    lstm_stage_mfma<<<sgrid,256,0,stream>>>(bufA, 512, 512, wp_d1,
        dec_b + 2048, hRb, hWb, dec_c, bufB, nullptr, 1);
    lstm_stage_mfma<<<sgrid,256,0,stream>>>(bufB, 512, 512, wp_d2,
        dec_b + 4096, hRb, hWb, dec_c, bufA, nullptr, 2);
    fc_kernel<<<BB, 256, 0, stream>>>(bufA, fc_W, fc_b, out, i);
  }
}